// Round 4
// baseline (31.655 us; speedup 1.0000x reference)
//
#include <hip/hip_runtime.h>

// Bezier2Image, fully fused:
//   res[b,w,v] = min(1, sum_k gX[b,w,k]*gY[b,v,k]),  k = (curve, sample)
// One block per batch (128 x 512 threads). Per 256-column K-chunk:
//  - scatter truncated 8px gaussian windows into a 64KB XOR-swizzled f16 LDS
//    tile (column-exclusive writes, zero-prev-window, no bulk re-zero)
//  - 8 waves each contract a disjoint 32-column K-slice into a full 64x64
//    fp32 accumulator using mfma_f32_32x32x16_f16 (2x2 fragments)
// Epilogue: LDS tree-reduce the 8 per-wave partials, clamp, store to out.

namespace {
constexpr int   kN = 30;              // samples per curve
constexpr int   kW = 60;              // image side
constexpr int   kL = 160;             // curves per batch
constexpr int   kB = 128;             // batch
constexpr float kAlphaInv = 5000.0f;  // 1/2e-4
constexpr float kRadPix = 3.5f;       // truncation radius in pixels
constexpr int   KC  = 256;            // k-columns per chunk (8 curves x 32)
constexpr int   NCH = kL * 32 / KC;   // 20 chunks (curves padded 30->32)
constexpr int   kPix = kW * kW;       // 3600
}

using f32x16 = __attribute__((ext_vector_type(16))) float;
using f16x8  = __attribute__((ext_vector_type(8))) _Float16;

// f16 element offset in the [2][64][256] staging tile, 16B-granule XOR swizzle:
// phys_granule = (col/8) ^ (row%8)  -> ds_read_b128 of a column-slice is
// conflict-free (row stride 512B alone would hit 4 banks).
__device__ __forceinline__ int lds_off(int mat, int row, int col) {
  int g = ((col >> 3) ^ row) & 31;            // col>>3 in 0..31; xor low 3 row bits
  g = ((col >> 3) & 24) | (((col >> 3) ^ row) & 7);
  return ((mat << 6) + row) * KC + (g << 3) + (col & 7);
}

__global__ __launch_bounds__(512, 1) void bezier_fused_kernel(const float* __restrict__ x,
                                                              float* __restrict__ out) {
  __shared__ _Float16 sh[2 * 64 * KC];   // 64 KB; reused as float[16384] in epilogue
  const int b    = blockIdx.x;
  const int tid  = threadIdx.x;
  const int lane = tid & 63;
  const int wid  = tid >> 6;             // 8 waves; wave = K-slice within chunk
  const int l31  = lane & 31;
  const int hi   = lane >> 5;

  f32x16 acc[2][2] = {};                 // full 64x64 per wave (fp32)

  const float* xb = x + (size_t)b * kL * 8;

  // ---- staging role: one (matrix, column) per thread ----
  const int col = tid & 255;
  const int mat = tid >> 8;              // 0 = gX (rows w), 1 = gY (rows v)
  const int n   = col & 31;              // sample index; 30,31 = zero pad
  const bool valid = (n < kN);
  float B0, B1, B2, B3;
  {
    float t0 = (float)n * (1.0f / 30.0f);
    float t  = 2.0f * t0 * t0 * t0 - 3.0f * t0 * t0 + 2.0f * t0;
    float t2 = t * t, t3 = t2 * t;
    B0 = t3;
    B1 = 3.0f * (t2 - t3);
    B2 = 3.0f * (t3 - 2.0f * t2 + t);
    float omt = 1.0f - t;
    B3 = omt * omt * omt;
  }
  int lo_prev = -1000;                   // first chunk: nothing to zero

  // ---- initial full zero of the staging tile ----
  {
    uint4* z = (uint4*)sh;
    for (int i = tid; i < 2 * 64 * KC * 2 / 16; i += 512) z[i] = make_uint4(0, 0, 0, 0);
  }
  __syncthreads();

  for (int ch = 0; ch < NCH; ++ch) {
    // ---- scatter (column-exclusive) ----
    if (valid) {
      const int lc = ch * 8 + (col >> 5);
      const float4* c = (const float4*)(xb + lc * 8);
      float4 c0 = c[0], c1 = c[1];
      float P = mat ? (B0 * c0.y + B1 * c0.w + B2 * c1.y + B3 * c1.w)
                    : (B0 * c0.x + B1 * c0.z + B2 * c1.x + B3 * c1.z);
      float fp = P * (float)kW;
      int lo = (int)ceilf(fp - kRadPix);
#pragma unroll
      for (int i = 0; i < 8; ++i) {      // zero own previous window
        int m = lo_prev + i;
        if (m >= 0 && m < kW) sh[lds_off(mat, m, col)] = (_Float16)0.0f;
      }
#pragma unroll
      for (int i = 0; i < 8; ++i) {      // write new window
        int m = lo + i;
        if (m >= 0 && m < kW) {
          float d = (float)m * (1.0f / 60.0f) - P;
          sh[lds_off(mat, m, col)] = (_Float16)__expf(-d * d * kAlphaInv);
        }
      }
      lo_prev = lo;
    }
    __syncthreads();

    // ---- MFMA: wave wid contracts k-slice [wid*32, wid*32+32) ----
#pragma unroll
    for (int ks = 0; ks < 2; ++ks) {
      const int gb = wid * 4 + ks * 2 + hi;          // 16B-granule index of k-start
      // A (gX): rows l31 / 32+l31 ; B (gY): same pattern (B = gY^T fragment)
      const int ra = ((0 << 6) + l31) * KC + ((((gb ^ l31) & 7) | (gb & 24)) << 3);
      const int rA = ((0 << 6) + 32 + l31) * KC + ((((gb ^ l31) & 7) | (gb & 24)) << 3);
      const int rb = ((1 << 6) + l31) * KC + ((((gb ^ l31) & 7) | (gb & 24)) << 3);
      const int rB = ((1 << 6) + 32 + l31) * KC + ((((gb ^ l31) & 7) | (gb & 24)) << 3);
      f16x8 a0 = *(const f16x8*)&sh[ra];
      f16x8 a1 = *(const f16x8*)&sh[rA];
      f16x8 b0 = *(const f16x8*)&sh[rb];
      f16x8 b1 = *(const f16x8*)&sh[rB];
      acc[0][0] = __builtin_amdgcn_mfma_f32_32x32x16_f16(a0, b0, acc[0][0], 0, 0, 0);
      acc[0][1] = __builtin_amdgcn_mfma_f32_32x32x16_f16(a0, b1, acc[0][1], 0, 0, 0);
      acc[1][0] = __builtin_amdgcn_mfma_f32_32x32x16_f16(a1, b0, acc[1][0], 0, 0, 0);
      acc[1][1] = __builtin_amdgcn_mfma_f32_32x32x16_f16(a1, b1, acc[1][1], 0, 0, 0);
    }
    __syncthreads();
  }

  // ---- epilogue: tree-reduce 8 wave partials in LDS (4 slots of 64x64 f32) ----
  float* red = (float*)sh;
  if (wid < 4) {                         // round 1: waves 0-3 store
    float* slot = red + wid * 4096;
#pragma unroll
    for (int mi = 0; mi < 2; ++mi)
#pragma unroll
      for (int vi = 0; vi < 2; ++vi)
#pragma unroll
        for (int r = 0; r < 16; ++r) {
          int row = mi * 32 + (r & 3) + 8 * (r >> 2) + 4 * hi;
          int cc  = vi * 32 + l31;
          slot[row * 64 + cc] = acc[mi][vi][r];
        }
  }
  __syncthreads();
  if (wid >= 4) {                        // round 2: waves 4-7 add into slots
    float* slot = red + (wid - 4) * 4096;
#pragma unroll
    for (int mi = 0; mi < 2; ++mi)
#pragma unroll
      for (int vi = 0; vi < 2; ++vi)
#pragma unroll
        for (int r = 0; r < 16; ++r) {
          int row = mi * 32 + (r & 3) + 8 * (r >> 2) + 4 * hi;
          int cc  = vi * 32 + l31;
          slot[row * 64 + cc] += acc[mi][vi][r];
        }
  }
  __syncthreads();

  float* ob = out + (size_t)b * kPix;
  for (int p = tid; p < kPix; p += 512) {
    int r = p / kW;
    int c = p - r * kW;
    int idx = r * 64 + c;
    float s = red[idx] + red[4096 + idx] + red[8192 + idx] + red[12288 + idx];
    ob[p] = fminf(s, 1.0f);
  }
}

extern "C" void kernel_launch(void* const* d_in, const int* in_sizes, int n_in,
                              void* d_out, int out_size, void* d_ws, size_t ws_size,
                              hipStream_t stream) {
  const float* x = (const float*)d_in[0];
  float* out = (float*)d_out;
  bezier_fused_kernel<<<dim3(kB), dim3(512), 0, stream>>>(x, out);
}

// Round 5
// 26.221 us; speedup vs baseline: 1.2072x; 1.2072x over previous
//
#include <hip/hip_runtime.h>

// Bezier2Image: res[b,w,v] = min(1, sum_k gX[b,w,k]*gY[b,v,k])
// Grid = 128 batches x 4 K-split blocks, 256 threads (4 waves).
// Per 128-col chunk: scatter truncated 8px gaussian windows into a 32KB
// XOR-swizzled f16 LDS tile (column-exclusive, zero-prev-window), then each
// wave contracts a disjoint 32-col K-slice into a FULL 64x64 fp32 acc with
// mfma_f32_32x32x16_f16 (A/B each read once per block). Waves tree-reduce in
// LDS, block stores one 3600-float partial; reduce kernel sums 4 + clamps.

namespace {
constexpr int   kN = 30;              // samples per curve
constexpr int   kW = 60;              // image side
constexpr int   kL = 160;             // curves per batch
constexpr int   kB = 128;             // batch
constexpr float kAlphaInv = 5000.0f;  // 1/2e-4
constexpr float kRadPix = 3.5f;       // truncation radius in pixels
constexpr int   KSPLIT = 4;           // K-split blocks per batch
constexpr int   CPB = kL / KSPLIT;    // 40 curves per block
constexpr int   KC  = 128;            // k-columns per chunk (4 curves x 32)
constexpr int   NCH = CPB * 32 / KC;  // 10 chunks
constexpr int   kPix = kW * kW;       // 3600
}

using f32x16 = __attribute__((ext_vector_type(16))) float;
using f16x8  = __attribute__((ext_vector_type(8))) _Float16;

// f16 element offset in [2][64][128] tile; 16B-granule XOR swizzle (low 3 bits
// of granule ^ low 3 bits of row) -> column-slice ds_read_b128 is 2-way max.
__device__ __forceinline__ int lds_off(int mat, int row, int col) {
  int g = col >> 3;                       // logical granule 0..15
  int gp = (g & 8) | ((g ^ row) & 7);     // physical granule
  return ((mat << 6) + row) * KC + (gp << 3) + (col & 7);
}

__global__ __launch_bounds__(256, 4) void bezier_gemm_kernel(const float* __restrict__ x,
                                                             float* __restrict__ partial) {
  __shared__ _Float16 sh[2 * 64 * KC];    // 32 KB; reused as float[8192] in epilogue
  const int b    = blockIdx.x / KSPLIT;
  const int ks   = blockIdx.x % KSPLIT;
  const int tid  = threadIdx.x;
  const int lane = tid & 63;
  const int wid  = tid >> 6;              // 4 waves; wave = 32-col K-slice
  const int l31  = lane & 31;
  const int hi   = lane >> 5;

  f32x16 acc[2][2] = {};                  // full 64x64 per wave

  const float* xb = x + ((size_t)b * kL + (size_t)ks * CPB) * 8;

  // staging role: one (matrix, column) per thread
  const int col = tid & 127;
  const int mat = tid >> 7;               // 0 = gX (rows w), 1 = gY (rows v)
  const int n   = col & 31;               // sample index; 30,31 = zero pad
  const bool valid = (n < kN);
  float B0, B1, B2, B3;
  {
    float t0 = (float)n * (1.0f / 30.0f);
    float t  = 2.0f * t0 * t0 * t0 - 3.0f * t0 * t0 + 2.0f * t0;
    float t2 = t * t, t3 = t2 * t;
    B0 = t3;
    B1 = 3.0f * (t2 - t3);
    B2 = 3.0f * (t3 - 2.0f * t2 + t);
    float omt = 1.0f - t;
    B3 = omt * omt * omt;
  }
  int lo_prev = -1000;                    // first chunk: nothing to zero

  // initial full zero of the staging tile
  {
    uint4* z = (uint4*)sh;
    for (int i = tid; i < 2 * 64 * KC * 2 / 16; i += 256) z[i] = make_uint4(0, 0, 0, 0);
  }
  __syncthreads();

  for (int ch = 0; ch < NCH; ++ch) {
    // ---- scatter (column-exclusive) ----
    if (valid) {
      const int lc = ch * 4 + (col >> 5);
      const float4* c = (const float4*)(xb + lc * 8);
      float4 c0 = c[0], c1 = c[1];
      float P = mat ? (B0 * c0.y + B1 * c0.w + B2 * c1.y + B3 * c1.w)
                    : (B0 * c0.x + B1 * c0.z + B2 * c1.x + B3 * c1.z);
      float fp = P * (float)kW;
      int lo = (int)ceilf(fp - kRadPix);
#pragma unroll
      for (int i = 0; i < 8; ++i) {       // zero own previous window
        int m = lo_prev + i;
        if (m >= 0 && m < kW) sh[lds_off(mat, m, col)] = (_Float16)0.0f;
      }
#pragma unroll
      for (int i = 0; i < 8; ++i) {       // write new window
        int m = lo + i;
        if (m >= 0 && m < kW) {
          float d = (float)m * (1.0f / 60.0f) - P;
          sh[lds_off(mat, m, col)] = (_Float16)__expf(-d * d * kAlphaInv);
        }
      }
      lo_prev = lo;
    }
    __syncthreads();

    // ---- MFMA: wave wid contracts cols [wid*32, wid*32+32) ----
#pragma unroll
    for (int kk = 0; kk < 2; ++kk) {
      const int gb = wid * 4 + kk * 2 + hi;           // logical granule of k-start
      const int gpA = ((gb & 8) | ((gb ^ l31) & 7)) << 3;
      const int ra = (l31)        * KC + gpA;         // gX row l31
      const int rA = (32 + l31)   * KC + gpA;         // gX row 32+l31 (same low3)
      const int rb = (64 + l31)   * KC + gpA;         // gY row l31
      const int rB = (96 + l31)   * KC + gpA;         // gY row 32+l31
      f16x8 a0 = *(const f16x8*)&sh[ra];
      f16x8 a1 = *(const f16x8*)&sh[rA];
      f16x8 b0 = *(const f16x8*)&sh[rb];
      f16x8 b1 = *(const f16x8*)&sh[rB];
      acc[0][0] = __builtin_amdgcn_mfma_f32_32x32x16_f16(a0, b0, acc[0][0], 0, 0, 0);
      acc[0][1] = __builtin_amdgcn_mfma_f32_32x32x16_f16(a0, b1, acc[0][1], 0, 0, 0);
      acc[1][0] = __builtin_amdgcn_mfma_f32_32x32x16_f16(a1, b0, acc[1][0], 0, 0, 0);
      acc[1][1] = __builtin_amdgcn_mfma_f32_32x32x16_f16(a1, b1, acc[1][1], 0, 0, 0);
    }
    __syncthreads();
  }

  // ---- epilogue: tree-reduce 4 wave partials in LDS (2 slots of 64x64 f32) ----
  float* red = (float*)sh;
  if (wid < 2) {
    float* slot = red + wid * 4096;
#pragma unroll
    for (int mi = 0; mi < 2; ++mi)
#pragma unroll
      for (int vi = 0; vi < 2; ++vi)
#pragma unroll
        for (int r = 0; r < 16; ++r) {
          int row = mi * 32 + (r & 3) + 8 * (r >> 2) + 4 * hi;
          slot[row * 64 + vi * 32 + l31] = acc[mi][vi][r];
        }
  }
  __syncthreads();
  if (wid >= 2) {
    float* slot = red + (wid - 2) * 4096;
#pragma unroll
    for (int mi = 0; mi < 2; ++mi)
#pragma unroll
      for (int vi = 0; vi < 2; ++vi)
#pragma unroll
        for (int r = 0; r < 16; ++r) {
          int row = mi * 32 + (r & 3) + 8 * (r >> 2) + 4 * hi;
          slot[row * 64 + vi * 32 + l31] += acc[mi][vi][r];
        }
  }
  __syncthreads();

  float* pb = partial + (size_t)blockIdx.x * kPix;
  for (int p = tid; p < kPix; p += 256) {
    int r = p / kW;
    int c = p - r * kW;
    int idx = r * 64 + c;
    pb[p] = red[idx] + red[4096 + idx];
  }
}

__global__ __launch_bounds__(256) void reduce_kernel(const float* __restrict__ partial,
                                                     float* __restrict__ out) {
  constexpr int F4 = kPix / 4;            // 900 float4 per image
  int i = blockIdx.x * 256 + threadIdx.x;
  if (i >= kB * F4) return;
  int b = i / F4;
  int j = i - b * F4;
  const float4* p = (const float4*)partial + (size_t)b * KSPLIT * F4 + j;
  float4 s0 = p[0], s1 = p[F4], s2 = p[2 * F4], s3 = p[3 * F4];
  float4 r;
  r.x = fminf(s0.x + s1.x + s2.x + s3.x, 1.0f);
  r.y = fminf(s0.y + s1.y + s2.y + s3.y, 1.0f);
  r.z = fminf(s0.z + s1.z + s2.z + s3.z, 1.0f);
  r.w = fminf(s0.w + s1.w + s2.w + s3.w, 1.0f);
  ((float4*)out)[i] = r;
}

// Fallback if ws is too small: one block per batch, LDS-atomic splat, direct write.
__global__ __launch_bounds__(1024) void splat_direct_kernel(const float* __restrict__ x,
                                                            float* __restrict__ out) {
  __shared__ float res[kPix];
  const int b = blockIdx.x;
  const int tid = threadIdx.x;
  for (int i = tid; i < kPix; i += 1024) res[i] = 0.0f;
  __syncthreads();
  const float* xb = x + (size_t)b * kL * 8;
  for (int p = tid; p < kL * kN; p += 1024) {
    int l = p / kN;
    int n = p - l * kN;
    float t0 = (float)n * (1.0f / 30.0f);
    float t  = 2.0f * t0 * t0 * t0 - 3.0f * t0 * t0 + 2.0f * t0;
    float t2 = t * t, t3 = t2 * t;
    float B0 = t3, B1 = 3.0f * (t2 - t3), B2 = 3.0f * (t3 - 2.0f * t2 + t);
    float omt = 1.0f - t, B3 = omt * omt * omt;
    const float4* c = (const float4*)(xb + l * 8);
    float4 c0 = c[0], c1 = c[1];
    float X = B0 * c0.x + B1 * c0.z + B2 * c1.x + B3 * c1.z;
    float Y = B0 * c0.y + B1 * c0.w + B2 * c1.y + B3 * c1.w;
    float fx = X * kW, fy = Y * kW;
    int wlo = (int)ceilf(fx - kRadPix), vlo = (int)ceilf(fy - kRadPix);
    for (int i = 0; i < 8; ++i) {
      int w = wlo + i;
      if (w < 0 || w >= kW) continue;
      float dw = ((float)w - fx) * (1.0f / kW);
      float gx = __expf(-dw * dw * kAlphaInv);
      for (int j = 0; j < 8; ++j) {
        int v = vlo + j;
        if (v < 0 || v >= kW) continue;
        float dv = ((float)v - fy) * (1.0f / kW);
        atomicAdd(&res[w * kW + v], gx * __expf(-dv * dv * kAlphaInv));
      }
    }
  }
  __syncthreads();
  float* outb = out + (size_t)b * kPix;
  for (int i = tid; i < kPix; i += 1024) outb[i] = fminf(res[i], 1.0f);
}

extern "C" void kernel_launch(void* const* d_in, const int* in_sizes, int n_in,
                              void* d_out, int out_size, void* d_ws, size_t ws_size,
                              hipStream_t stream) {
  const float* x = (const float*)d_in[0];
  float* out = (float*)d_out;
  const size_t part_bytes = (size_t)kB * KSPLIT * kPix * sizeof(float);

  if (ws_size >= part_bytes) {
    float* partial = (float*)d_ws;
    bezier_gemm_kernel<<<dim3(kB * KSPLIT), dim3(256), 0, stream>>>(x, partial);
    int n4 = kB * kPix / 4;
    reduce_kernel<<<dim3((n4 + 255) / 256), dim3(256), 0, stream>>>(partial, out);
  } else {
    splat_direct_kernel<<<dim3(kB), dim3(1024), 0, stream>>>(x, out);
  }
}